// Round 8
// baseline (252.971 us; speedup 1.0000x reference)
//
#include <hip/hip_runtime.h>

#define NN 50000
#define EE 800000

#define BKT 196      // buckets = dst>>8 (256 nodes each)
#define GB  334      // histogram/scatter blocks
#define EPB 2396     // edges per block (334*2396 = 800264 >= E)
#define CAP 5120     // LDS staging capacity per bucket (mean 4081)

typedef unsigned short u16;
typedef unsigned int u32;
typedef __attribute__((ext_vector_type(8))) short short8;   // 8 bf16 (4 VGPRs)
typedef __attribute__((ext_vector_type(4))) float f32x4;
typedef __attribute__((ext_vector_type(4))) unsigned short ushort4v;

__device__ __forceinline__ float b2f(u16 u) {
    return __uint_as_float(((unsigned)u) << 16);
}
__device__ __forceinline__ u16 f2b(float f) {
    unsigned u = __float_as_uint(f);
    return (u16)((u + 0x7FFF + ((u >> 16) & 1)) >> 16);   // RNE
}

// ---------------------------------------------------------------------------
// pack W0/W1/W2(padded) into MFMA B-fragment order (bf16)
// ---------------------------------------------------------------------------
__global__ __launch_bounds__(64) void prep_w(
    const float* __restrict__ W0, const float* __restrict__ W1,
    const float* __restrict__ W2, u16* __restrict__ Wf)
{
    int b = blockIdx.x;
    int set = b >> 5, nt = (b >> 2) & 7, kt = b & 3;
    int lane = threadIdx.x;
    const float* W = (set == 0) ? W0 : (set == 1) ? W1 : W2;
    int ld = (set == 2) ? 40 : 128;
    int ncols = (set == 2) ? 40 : 128;
    int n = nt * 16 + (lane & 15);
    int kbase = kt * 32 + (lane >> 4) * 8;
    u16* dst = Wf + set * 16384 + (size_t)((nt * 4 + kt) * 64 + lane) * 8;
#pragma unroll
    for (int j = 0; j < 8; j++) {
        float v = (n < ncols) ? W[(kbase + j) * ld + n] : 0.f;
        dst[j] = f2b(v);
    }
}

// ---------------------------------------------------------------------------
// layer-0 GEMM: t[n][m] = sum_k bf16(x[n][k]) * W0[k][m]   (fp32 input)
// ---------------------------------------------------------------------------
__global__ __launch_bounds__(256) void gemm0(
    const float* __restrict__ A, const u16* __restrict__ Wf,
    u16* __restrict__ out, int N)
{
    const int wave = threadIdx.x >> 6;
    const int lane = threadIdx.x & 63;
    const int m = lane & 15;
    const int q = lane >> 4;
    const int rowBase = blockIdx.x * 64 + wave * 16;
    const int arow = rowBase + m;
    const bool rowOk = (arow < N);

    short8 af[4];
#pragma unroll
    for (int kt = 0; kt < 4; kt++) {
        if (rowOk) {
            float4 lo = *(const float4*)(A + (size_t)arow * 128 + kt * 32 + q * 8);
            float4 hi = *(const float4*)(A + (size_t)arow * 128 + kt * 32 + q * 8 + 4);
            short8 v;
            v[0] = (short)f2b(lo.x); v[1] = (short)f2b(lo.y);
            v[2] = (short)f2b(lo.z); v[3] = (short)f2b(lo.w);
            v[4] = (short)f2b(hi.x); v[5] = (short)f2b(hi.y);
            v[6] = (short)f2b(hi.z); v[7] = (short)f2b(hi.w);
            af[kt] = v;
        } else {
            af[kt] = (short8)0;
        }
    }

    f32x4 acc[8];
#pragma unroll
    for (int nt = 0; nt < 8; nt++) acc[nt] = (f32x4)0.f;

#pragma unroll
    for (int kt = 0; kt < 4; kt++) {
#pragma unroll
        for (int nt = 0; nt < 8; nt++) {
            short8 bf = *(const short8*)(Wf + (size_t)((nt * 4 + kt) * 64 + lane) * 8);
            acc[nt] = __builtin_amdgcn_mfma_f32_16x16x32_bf16(af[kt], bf, acc[nt], 0, 0, 0);
        }
    }

#pragma unroll
    for (int nt = 0; nt < 8; nt++) {
#pragma unroll
        for (int r = 0; r < 4; r++) {
            int orow = rowBase + q * 4 + r;
            if (orow < N) out[(size_t)orow * 128 + nt * 16 + m] = f2b(acc[nt][r]);
        }
    }
}

// ---------------------------------------------------------------------------
// GEMM from bf16 rows (stride 128): out = A @ W, NT n-tiles, OSTRIDE out cols
// ---------------------------------------------------------------------------
template<int NT, int OSTRIDE>
__global__ __launch_bounds__(256) void gemm_b(
    const u16* __restrict__ A, const u16* __restrict__ Wf,
    u16* __restrict__ out, int N)
{
    const int wave = threadIdx.x >> 6;
    const int lane = threadIdx.x & 63;
    const int m = lane & 15;
    const int q = lane >> 4;
    const int rowBase = blockIdx.x * 64 + wave * 16;
    const int arow = rowBase + m;
    const bool rowOk = (arow < N);

    short8 af[4];
#pragma unroll
    for (int kt = 0; kt < 4; kt++) {
        af[kt] = rowOk ? *(const short8*)(A + (size_t)arow * 128 + kt * 32 + q * 8)
                       : (short8)0;
    }

    f32x4 acc[NT];
#pragma unroll
    for (int nt = 0; nt < NT; nt++) acc[nt] = (f32x4)0.f;

#pragma unroll
    for (int kt = 0; kt < 4; kt++) {
#pragma unroll
        for (int nt = 0; nt < NT; nt++) {
            short8 bf = *(const short8*)(Wf + (size_t)((nt * 4 + kt) * 64 + lane) * 8);
            acc[nt] = __builtin_amdgcn_mfma_f32_16x16x32_bf16(af[kt], bf, acc[nt], 0, 0, 0);
        }
    }

#pragma unroll
    for (int nt = 0; nt < NT; nt++) {
#pragma unroll
        for (int r = 0; r < 4; r++) {
            int orow = rowBase + q * 4 + r;
            if (orow < N) out[(size_t)orow * OSTRIDE + nt * 16 + m] = f2b(acc[nt][r]);
        }
    }
}

// ---------------------------------------------------------------------------
// CSR build, pass 1: per-block LDS histogram over 196 buckets (dst>>8)
// ---------------------------------------------------------------------------
__global__ __launch_bounds__(256) void hist_buckets(
    const int* __restrict__ dst, int* __restrict__ BBC, int E)
{
    __shared__ int cnt[BKT];
    const int g = blockIdx.x, t = threadIdx.x;
    for (int b = t; b < BKT; b += 256) cnt[b] = 0;
    __syncthreads();
    const int beg = g * EPB, end = min(E, beg + EPB);
    for (int e = beg + t; e < end; e += 256)
        atomicAdd(&cnt[dst[e] >> 8], 1);
    __syncthreads();
    for (int b = t; b < BKT; b += 256) BBC[b * GB + g] = cnt[b];
}

__global__ __launch_bounds__(1024) void block_scan(
    const int* __restrict__ in, int* __restrict__ out,
    int* __restrict__ blockSums, int M)
{
    __shared__ int sh[1024];
    const int t = threadIdx.x;
    const int idx = blockIdx.x * 1024 + t;
    const int v = (idx < M) ? in[idx] : 0;
    sh[t] = v;
    __syncthreads();
    for (int d = 1; d < 1024; d <<= 1) {
        int u = (t >= d) ? sh[t - d] : 0;
        __syncthreads();
        sh[t] += u;
        __syncthreads();
    }
    if (idx < M) out[idx] = sh[t] - v;
    if (t == 1023) blockSums[blockIdx.x] = sh[t];
}

__global__ __launch_bounds__(64) void scan_sums(
    int* __restrict__ blockSums, int nb)
{
    const int t = threadIdx.x;
    const int orig = (t < nb) ? blockSums[t] : 0;
    int v = orig;
#pragma unroll
    for (int d = 1; d < 64; d <<= 1) {
        int u = __shfl_up(v, d);
        if (t >= d) v += u;
    }
    if (t < nb) blockSums[t] = v - orig;
}

__global__ __launch_bounds__(1024) void add_base(
    int* __restrict__ S, const int* __restrict__ blockSums, int M)
{
    const int idx = blockIdx.x * 1024 + threadIdx.x;
    if (idx < M) S[idx] += blockSums[blockIdx.x];
}

// ---------------------------------------------------------------------------
// CSR build, pass 2: scatter packed (src<<8 | dst&255) into per-(bucket,block)
// segments. src < 2^16 so it fits 24 bits.
// ---------------------------------------------------------------------------
__global__ __launch_bounds__(256) void scatter_pairs(
    const int* __restrict__ src, const int* __restrict__ dst,
    const int* __restrict__ S, u32* __restrict__ pairs, int E)
{
    __shared__ int cur[BKT];
    const int g = blockIdx.x, t = threadIdx.x;
    for (int b = t; b < BKT; b += 256) cur[b] = S[b * GB + g];
    __syncthreads();
    const int beg = g * EPB, end = min(E, beg + EPB);
    for (int e = beg + t; e < end; e += 256) {
        int d = dst[e];
        int pos = atomicAdd(&cur[d >> 8], 1);
        pairs[pos] = ((u32)src[e] << 8) | (u32)(d & 255);
    }
}

// ---------------------------------------------------------------------------
// CSR build, pass 3: per-bucket node sort, fully LDS-staged
// ---------------------------------------------------------------------------
__global__ __launch_bounds__(256) void bucket_sort(
    const u32* __restrict__ pairs, const int* __restrict__ S,
    int* __restrict__ off, int* __restrict__ csr, int N, int E)
{
    __shared__ int sdeg[256];
    __shared__ int sex[256];
    __shared__ int scur[256];
    __shared__ int stage[CAP];
    const int b = blockIdx.x, t = threadIdx.x;
    const int base = S[b * GB];
    const int end  = (b == BKT - 1) ? E : S[(b + 1) * GB];
    const int cnt = end - base;

    sdeg[t] = 0;
    __syncthreads();
    for (int i = t; i < cnt; i += 256)
        atomicAdd(&sdeg[pairs[base + i] & 255], 1);
    __syncthreads();

    int v = sdeg[t];
    sex[t] = v;
    __syncthreads();
    for (int d = 1; d < 256; d <<= 1) {
        int u = (t >= d) ? sex[t - d] : 0;
        __syncthreads();
        sex[t] += u;
        __syncthreads();
    }
    const int excl = sex[t] - v;
    const int node = b * 256 + t;
    if (node < N) off[node] = base + excl;
    if (b == BKT - 1 && t == 0) off[N] = E;
    scur[t] = excl;
    __syncthreads();

    if (cnt <= CAP) {
        for (int i = t; i < cnt; i += 256) {
            u32 p = pairs[base + i];
            int pos = atomicAdd(&scur[p & 255], 1);
            stage[pos] = (int)(p >> 8);
        }
        __syncthreads();
        for (int i = t; i < cnt; i += 256) csr[base + i] = stage[i];
    } else {
        for (int i = t; i < cnt; i += 256) {
            u32 p = pairs[base + i];
            int pos = atomicAdd(&scur[p & 255], 1);
            csr[base + pos] = (int)(p >> 8);
        }
    }
}

// ---------------------------------------------------------------------------
// chunked aggregation: grid (N/32, 4). Chunk = 32 feats (64 B of bf16 row).
// Reuse distance per XCD drops to ~3.2 MB < 4 MB L2 -> re-gathers hit L2.
// block = 32 nodes x 8 lanes; lane reads ushort4 (8 B).
// out[node][f] = bf16( relu( sum_e val[src][f] + bias[f] ) ), stride 128
// ---------------------------------------------------------------------------
__global__ __launch_bounds__(256) void agg_chunk(
    const u16* __restrict__ val, const int* __restrict__ off,
    const int* __restrict__ csr, const float* __restrict__ bias,
    u16* __restrict__ out, int N)
{
    const int l = threadIdx.x & 7;
    const int node = blockIdx.x * 32 + (threadIdx.x >> 3);
    if (node >= N) return;
    const int fb = blockIdx.y * 32 + l * 4;    // feature base
    const int beg = off[node], end = off[node + 1];

    float a0[4] = {0, 0, 0, 0};
    float a1[4] = {0, 0, 0, 0};
    int i = beg;
    for (; i + 3 < end; i += 4) {
        int s0 = csr[i];
        int s1 = csr[i + 1];
        int s2 = csr[i + 2];
        int s3 = csr[i + 3];
        ushort4v v0 = *(const ushort4v*)(val + (size_t)s0 * 128 + fb);
        ushort4v v1 = *(const ushort4v*)(val + (size_t)s1 * 128 + fb);
        ushort4v v2 = *(const ushort4v*)(val + (size_t)s2 * 128 + fb);
        ushort4v v3 = *(const ushort4v*)(val + (size_t)s3 * 128 + fb);
        a0[0] += b2f(v0.x) + b2f(v2.x); a0[1] += b2f(v0.y) + b2f(v2.y);
        a0[2] += b2f(v0.z) + b2f(v2.z); a0[3] += b2f(v0.w) + b2f(v2.w);
        a1[0] += b2f(v1.x) + b2f(v3.x); a1[1] += b2f(v1.y) + b2f(v3.y);
        a1[2] += b2f(v1.z) + b2f(v3.z); a1[3] += b2f(v1.w) + b2f(v3.w);
    }
    for (; i < end; i++) {
        int s0 = csr[i];
        ushort4v v0 = *(const ushort4v*)(val + (size_t)s0 * 128 + fb);
        a0[0] += b2f(v0.x); a0[1] += b2f(v0.y);
        a0[2] += b2f(v0.z); a0[3] += b2f(v0.w);
    }

    float4 b = *(const float4*)(bias + fb);
    ushort4v o;
    o.x = f2b(fmaxf(a0[0] + a1[0] + b.x, 0.f));
    o.y = f2b(fmaxf(a0[1] + a1[1] + b.y, 0.f));
    o.z = f2b(fmaxf(a0[2] + a1[2] + b.z, 0.f));
    o.w = f2b(fmaxf(a0[3] + a1[3] + b.w, 0.f));
    *(ushort4v*)(out + (size_t)node * 128 + fb) = o;
}

// ---------------------------------------------------------------------------
// aggregate first 40 feats of bf16 stride-48 rows, + b2 -> fp32 d_out
// ---------------------------------------------------------------------------
__global__ __launch_bounds__(256) void agg40b(
    const u16* __restrict__ val, const int* __restrict__ off,
    const int* __restrict__ csr_src, const float* __restrict__ b2,
    float* __restrict__ out, int N)
{
    const int c = threadIdx.x & 15;
    const int node = blockIdx.x * 16 + (threadIdx.x >> 4);
    if (node >= N || c >= 10) return;
    const int beg = off[node], end = off[node + 1];

    float a0[4] = {0, 0, 0, 0};
    float a1[4] = {0, 0, 0, 0};
    int i = beg;
    for (; i + 1 < end; i += 2) {
        int s0 = csr_src[i];
        int s1 = csr_src[i + 1];
        ushort4v v0 = *(const ushort4v*)(val + (size_t)s0 * 48 + c * 4);
        ushort4v v1 = *(const ushort4v*)(val + (size_t)s1 * 48 + c * 4);
        a0[0] += b2f(v0.x); a0[1] += b2f(v0.y); a0[2] += b2f(v0.z); a0[3] += b2f(v0.w);
        a1[0] += b2f(v1.x); a1[1] += b2f(v1.y); a1[2] += b2f(v1.z); a1[3] += b2f(v1.w);
    }
    if (i < end) {
        int s0 = csr_src[i];
        ushort4v v0 = *(const ushort4v*)(val + (size_t)s0 * 48 + c * 4);
        a0[0] += b2f(v0.x); a0[1] += b2f(v0.y); a0[2] += b2f(v0.z); a0[3] += b2f(v0.w);
    }
    float4 b = *(const float4*)(b2 + c * 4);
    float4 r;
    r.x = a0[0] + a1[0] + b.x;
    r.y = a0[1] + a1[1] + b.y;
    r.z = a0[2] + a1[2] + b.z;
    r.w = a0[3] + a1[3] + b.w;
    *(float4*)(out + (size_t)node * 40 + c * 4) = r;
}

extern "C" void kernel_launch(void* const* d_in, const int* in_sizes, int n_in,
                              void* d_out, int out_size, void* d_ws, size_t ws_size,
                              hipStream_t stream)
{
    const float* x  = (const float*)d_in[0];
    const int*   ei = (const int*)d_in[1];
    const float* W0 = (const float*)d_in[2];
    const float* b0 = (const float*)d_in[3];
    const float* W1 = (const float*)d_in[4];
    const float* b1 = (const float*)d_in[5];
    const float* W2 = (const float*)d_in[6];
    const float* b2 = (const float*)d_in[7];
    float* out = (float*)d_out;

    const int N = NN, E = EE;
    const int* src = ei;        // edge_index[0]
    const int* dst = ei + E;    // edge_index[1]

    char* ws = (char*)d_ws;
    u16* t       = (u16*)ws;                        // 12.8 MB (GEMM out)
    u16* hb      = (u16*)(ws + 12800000);           // 12.8 MB (agg out)
    u16* t2      = (u16*)(ws + 25600000);           // 4.8 MB (layer-2 GEMM out)
    u16* Wf      = (u16*)(ws + 30400000);           // 96 KB (frag-packed W)
    int* off     = (int*)(ws + 30500000);           // 200 KB (N+1)
    int* csr_src = (int*)(ws + 30700008);           // 3.2 MB
    int* BBC     = (int*)(ws + 33900008);           // 262 KB
    int* S       = (int*)(ws + 34161864);           // 262 KB
    int* blkSums = (int*)(ws + 34423720);           // 256 B
    u32* pairs   = (u32*)(ws + 34423976);           // 3.2 MB (packed)

    const int M = BKT * GB;                         // 65464
    const int nScan = (M + 1023) / 1024;            // 64
    const int tileGrid = (N + 63) / 64;             // 782
    const int aggGrid = (N + 31) / 32;              // 1563
    const int agg40Grid = (N + 15) / 16;            // 3125

    // ---- CSR build: LDS-staged bucketed counting sort
    hist_buckets<<<GB, 256, 0, stream>>>(dst, BBC, E);
    block_scan<<<nScan, 1024, 0, stream>>>(BBC, S, blkSums, M);
    scan_sums<<<1, 64, 0, stream>>>(blkSums, nScan);
    add_base<<<nScan, 1024, 0, stream>>>(S, blkSums, M);
    scatter_pairs<<<GB, 256, 0, stream>>>(src, dst, S, pairs, E);
    bucket_sort<<<BKT, 256, 0, stream>>>(pairs, S, off, csr_src, N, E);

    // ---- weight prep
    prep_w<<<96, 64, 0, stream>>>(W0, W1, W2, Wf);

    // ---- layer 0: t = bf16(x) @ W0
    gemm0<<<tileGrid, 256, 0, stream>>>(x, Wf, t, N);

    // ---- layer 1: hb = relu(agg(t) + b0) ; t = hb @ W1
    agg_chunk<<<dim3(aggGrid, 4), 256, 0, stream>>>(t, off, csr_src, b0, hb, N);
    gemm_b<8, 128><<<tileGrid, 256, 0, stream>>>(hb, Wf + 16384, t, N);

    // ---- layer 2: hb = relu(agg(t) + b1) ; t2 = hb @ W2pad (48 cols)
    agg_chunk<<<dim3(aggGrid, 4), 256, 0, stream>>>(t, off, csr_src, b1, hb, N);
    gemm_b<3, 48><<<tileGrid, 256, 0, stream>>>(hb, Wf + 32768, t2, N);

    // ---- final: out = agg40(t2) + b2
    agg40b<<<agg40Grid, 256, 0, stream>>>(t2, off, csr_src, b2, out, N);
}